// Round 8
// baseline (200.682 us; speedup 1.0000x reference)
//
#include <hip/hip_runtime.h>
#include <math.h>

#define EPS 1e-5f

__device__ __forceinline__ float wave_sum(float v) {
  v += __shfl_down(v, 32);
  v += __shfl_down(v, 16);
  v += __shfl_down(v, 8);
  v += __shfl_down(v, 4);
  v += __shfl_down(v, 2);
  v += __shfl_down(v, 1);
  return v;
}

__device__ __forceinline__ float silu_f(float v) { return v / (1.f + __expf(-v)); }
__device__ __forceinline__ float sigm_f(float v) { return 1.f / (1.f + __expf(-v)); }

__device__ __forceinline__ int bitrev6(int v) {
  return ((v & 1) << 5) | ((v & 2) << 3) | ((v & 4) << 1) |
         ((v & 8) >> 1) | ((v & 16) >> 3) | ((v & 32) >> 5);
}

#define FFT6(zr, zi)                                           \
  do {                                                         \
    _Pragma("unroll") for (int s = 0; s < 6; ++s) {            \
      const int half = 32 >> s;                                \
      const bool up = (lane & half) != 0;                      \
      float pr = __shfl_xor(zr, half);                         \
      float pi = __shfl_xor(zi, half);                         \
      float tr = up ? pr - zr : zr + pr;                       \
      float ti = up ? pi - zi : zi + pi;                       \
      const float c = twc[s], sn = tws[s];                     \
      zr = tr * c - ti * sn;                                   \
      zi = tr * sn + ti * c;                                   \
    }                                                          \
  } while (0)

// ---------------------------------------------------------------------------
// Kernel A: per-(b,c) mean |2D-DFT| + spatial mean (R5 version, standalone).
// ---------------------------------------------------------------------------
__global__ __launch_bounds__(256) void k_dft(const float* __restrict__ x,
                                             float* __restrict__ energy,
                                             float* __restrict__ meanx) {
  __shared__ float re1[33 * 65];   // [kv 0..32][h]
  __shared__ float im1[33 * 65];
  __shared__ float redA[4], redB[4];
  const int bc = blockIdx.x;       // b*64 + c
  const int tid = threadIdx.x;
  const int lane = tid & 63;
  const int wv = tid >> 6;         // wave 0..3
  const float* xp = x + (size_t)bc * 4096;

  float twc[6], tws[6];
#pragma unroll
  for (int s = 0; s < 6; ++s) {
    int half = 32 >> s;
    if (lane & half) {
      float ang = -6.283185307179586f * (float)((lane & (half - 1)) << s) / 64.f;
      float sv, cv;
      __sincosf(ang, &sv, &cv);
      twc[s] = cv;
      tws[s] = sv;
    } else {
      twc[s] = 1.f;
      tws[s] = 0.f;
    }
  }

  const int f = bitrev6(lane);
  const int fm = (64 - f) & 63;
  const int plane = bitrev6(fm);

  float lsum = 0.f;
#pragma unroll 1
  for (int rp = 0; rp < 4; ++rp) {
    const int h0 = wv * 16 + rp * 4;
    float x0 = xp[h0 * 64 + lane];
    float x1 = xp[(h0 + 1) * 64 + lane];
    float x2 = xp[(h0 + 2) * 64 + lane];
    float x3 = xp[(h0 + 3) * 64 + lane];
    lsum += x0 + x1 + x2 + x3;
    float zr = x0, zi = x1, yr = x2, yi = x3;
#pragma unroll
    for (int s = 0; s < 6; ++s) {
      const int half = 32 >> s;
      const bool up = (lane & half) != 0;
      float pzr = __shfl_xor(zr, half);
      float pzi = __shfl_xor(zi, half);
      float pyr = __shfl_xor(yr, half);
      float pyi = __shfl_xor(yi, half);
      float tzr = up ? pzr - zr : zr + pzr;
      float tzi = up ? pzi - zi : zi + pzi;
      float tyr = up ? pyr - yr : yr + pyr;
      float tyi = up ? pyi - yi : yi + pyi;
      const float c = twc[s], sn = tws[s];
      zr = tzr * c - tzi * sn;
      zi = tzr * sn + tzi * c;
      yr = tyr * c - tyi * sn;
      yi = tyr * sn + tyi * c;
    }
    float mzr = __shfl(zr, plane), mzi = __shfl(zi, plane);
    float myr = __shfl(yr, plane), myi = __shfl(yi, plane);
    if (f <= 32) {
      float ar = 0.5f * (zr + mzr), ai = 0.5f * (zi - mzi);
      float br = 0.5f * (zi + mzi), bi = 0.5f * (mzr - zr);
      float cr = 0.5f * (yr + myr), ci = 0.5f * (yi - myi);
      float dr = 0.5f * (yi + myi), di = 0.5f * (myr - yr);
      re1[f * 65 + h0] = ar;     im1[f * 65 + h0] = ai;
      re1[f * 65 + h0 + 1] = br; im1[f * 65 + h0 + 1] = bi;
      re1[f * 65 + h0 + 2] = cr; im1[f * 65 + h0 + 2] = ci;
      re1[f * 65 + h0 + 3] = dr; im1[f * 65 + h0 + 3] = di;
    }
  }
  __syncthreads();

  float msum = 0.f;
#pragma unroll 1
  for (int i = 0; i < 4; ++i) {
    const int kv1 = wv + 8 * i;
    const int kv2 = kv1 + 4;
    const float w1 = (kv1 == 0) ? 1.f : 2.f;
    float ar = re1[kv1 * 65 + lane];
    float ai = im1[kv1 * 65 + lane];
    float br = re1[kv2 * 65 + lane];
    float bi = im1[kv2 * 65 + lane];
#pragma unroll
    for (int s = 0; s < 6; ++s) {
      const int half = 32 >> s;
      const bool up = (lane & half) != 0;
      float par = __shfl_xor(ar, half);
      float pai = __shfl_xor(ai, half);
      float pbr = __shfl_xor(br, half);
      float pbi = __shfl_xor(bi, half);
      float tar = up ? par - ar : ar + par;
      float tai = up ? pai - ai : ai + pai;
      float tbr = up ? pbr - br : br + pbr;
      float tbi = up ? pbi - bi : bi + pbi;
      const float c = twc[s], sn = tws[s];
      ar = tar * c - tai * sn;
      ai = tar * sn + tai * c;
      br = tbr * c - tbi * sn;
      bi = tbr * sn + tbi * c;
    }
    msum += w1 * sqrtf(ar * ar + ai * ai) + 2.f * sqrtf(br * br + bi * bi);
  }
  if (wv == 0) {
    float ar = re1[32 * 65 + lane];
    float ai = im1[32 * 65 + lane];
    FFT6(ar, ai);
    msum += sqrtf(ar * ar + ai * ai);
  }

  msum = wave_sum(msum);
  lsum = wave_sum(lsum);
  if (lane == 0) { redA[wv] = msum; redB[wv] = lsum; }
  __syncthreads();
  if (tid == 0) {
    float e = redA[0] + redA[1] + redA[2] + redA[3];
    float m = redB[0] + redB[1] + redB[2] + redB[3];
    energy[bc] = e * (1.f / 4096.f);
    meanx[bc] = m * (1.f / 4096.f);
  }
}

// ---------------------------------------------------------------------------
// Kernel B: per-batch channel attention head (R5 standalone version).
// ---------------------------------------------------------------------------
__global__ __launch_bounds__(64) void k_attn(
    const float* __restrict__ energy, const float* __restrict__ meanx,
    const float* __restrict__ ex_w, const float* __restrict__ ey_w,
    const float* __restrict__ ez_w, const float* __restrict__ ff_w,
    const float* __restrict__ ff_b, const float* __restrict__ g1_w,
    const float* __restrict__ g1_b, const float* __restrict__ g2_w,
    const float* __restrict__ g2_b, float* __restrict__ s2) {
  __shared__ float e[64], mx[64], my[64], mz[64];
  __shared__ float ax[64], ay[64], az[64], af[64], h1[16];
  const int b = blockIdx.x;
  const int c = threadIdx.x;
  e[c] = energy[b * 64 + c];
  mx[c] = meanx[b * 64 + c];
  __syncthreads();
  int rank = 0;
  float ec = e[c];
  for (int i = 0; i < 64; ++i) {
    float ei = e[i];
    rank += (ei > ec) || (ei == ec && i < c);
  }
  float mask = (rank < 32) ? 1.f : 0.f;
  my[c] = mx[c] * mask;
  mz[c] = mx[c] * (1.f - mask);
  __syncthreads();
  {
    float l, r, m;
    l = (c > 0) ? mx[c - 1] : 0.f; m = mx[c]; r = (c < 63) ? mx[c + 1] : 0.f;
    ax[c] = sigm_f(ex_w[0] * l + ex_w[1] * m + ex_w[2] * r);
    l = (c > 0) ? my[c - 1] : 0.f; m = my[c]; r = (c < 63) ? my[c + 1] : 0.f;
    ay[c] = sigm_f(ey_w[0] * l + ey_w[1] * m + ey_w[2] * r);
    l = (c > 0) ? mz[c - 1] : 0.f; m = mz[c]; r = (c < 63) ? mz[c + 1] : 0.f;
    az[c] = sigm_f(ez_w[0] * l + ez_w[1] * m + ez_w[2] * r);
  }
  __syncthreads();
  {
    int g = c >> 4;
    float acc = ff_b[c];
#pragma unroll
    for (int i = 0; i < 32; ++i) {
      int ch = g * 32 + i;
      float v = (ch < 64) ? ay[ch] : az[ch - 64];
      acc = fmaf(v, ff_w[c * 32 + i], acc);
    }
    af[c] = acc;
  }
  __syncthreads();
  if (c < 16) {
    float a = g1_b[c];
#pragma unroll
    for (int i = 0; i < 64; ++i) a = fmaf(af[i], g1_w[c * 128 + i], a);
#pragma unroll
    for (int i = 0; i < 64; ++i) a = fmaf(ax[i], g1_w[c * 128 + 64 + i], a);
    h1[c] = silu_f(a);
  }
  __syncthreads();
  float gv = g2_b[c];
#pragma unroll
  for (int o = 0; o < 16; ++o) gv = fmaf(h1[o], g2_w[c * 16 + o], gv);
  gv = sigm_f(gv);
  s2[b * 64 + c] = gv * af[c] + (1.f - gv) * ax[c];
}

// ---------------------------------------------------------------------------
// Kernel C: fused ReceptiveFieldAttentionConv.
// R7: icg-split-4 at P=2. 1024 blocks (2-row bands); 4 waves/block each
// handle 4 icgs for the SAME 128 pixels -> 16 waves/CU (4 blocks/CU by LDS)
// at constant total LDS-broadcast traffic and R5's proven ~60-VGPR register
// footprint (acc stays 32 floats). Merge via LDS atomicAdd (ds_add_f32)
// into a zero-init 128x33 buffer (stride-33: 2-way banks, free); waves 0/1
// run the two row epilogues from live registers + buffer.
// ---------------------------------------------------------------------------
__global__ __launch_bounds__(256) void k_rfa(
    const float* __restrict__ x,
    const float* __restrict__ sc_w, const float* __restrict__ sc_b,
    const float* __restrict__ ac_w, const float* __restrict__ ac_b,
    const float* __restrict__ oc_w, const float* __restrict__ oc_b,
    const float* __restrict__ bn_g, const float* __restrict__ bn_b,
    const float* __restrict__ bn_m, const float* __restrict__ bn_v,
    float* __restrict__ xrfa) {
  __shared__ __align__(16) float scwp[16 * 9 * 12];    // taps 0..8, bias at [9]
  __shared__ __align__(16) float mp[16 * 24];          // acw [0..8], acb [12..20]
  __shared__ __align__(16) float ocwp[16 * 16 * 12];
  __shared__ float mbuf[128 * 33];                     // 16.9 KB merge buffer
  const int blk = blockIdx.x;          // 1024 blocks: 32 bands x 4 g x 8 b
  const int band = blk & 31;
  const int g = (blk >> 5) & 3;
  const int b = blk >> 7;
  const int tid = threadIdx.x;
  const int lane = tid & 63;
  const int wv = tid >> 6;             // 0..3 = icg quartet

  // ---- stage packed weights + zero merge buffer ----
  for (int i = tid; i < 1296; i += 256) {
    int icg = i / 81, rem = i - icg * 81;
    int j = rem / 9, t = rem - j * 9;
    scwp[icg * 108 + j * 12 + t] = sc_w[(g * 144 + icg * 9 + j) * 9 + t];
  }
  if (tid < 144) {
    int icg = tid / 9, j = tid - icg * 9;
    scwp[icg * 108 + j * 12 + 9] = sc_b[g * 144 + tid];
    mp[icg * 24 + j] = ac_w[g * 144 + tid];
    mp[icg * 24 + 12 + j] = ac_b[g * 144 + tid];
  }
  for (int i = tid; i < 2304; i += 256) {
    int oco = i / 144, rem = i - oco * 144;
    int icg = rem / 9, j = rem - icg * 9;
    ocwp[icg * 192 + oco * 12 + j] = oc_w[((g * 16 + oco) * 16 + icg) * 9 + j];
  }
  for (int i = tid; i < 128 * 33; i += 256) mbuf[i] = 0.f;
  __syncthreads();

  const int r0 = band * 2;
  const int w = lane;
  const bool vW = w > 0, vE = w < 63;
  float acc0[16], acc1[16];
#pragma unroll
  for (int i = 0; i < 16; ++i) { acc0[i] = 0.f; acc1[i] = 0.f; }

  const float* xg = x + ((size_t)(b * 64 + g * 16)) * 4096 + w;
  const int icg0 = wv * 4;

#pragma unroll 1
  for (int ii = 0; ii < 4; ++ii) {
    const int icg = icg0 + ii;
    const float* xc = xg + icg * 4096;
    float n[12];
#pragma unroll
    for (int t = 0; t < 4; ++t) {
      int h = r0 - 1 + t;
      bool vh = (h >= 0) && (h < 64);
      const float* row = xc + h * 64;
      n[t * 3 + 0] = (vh && vW) ? row[-1] : 0.f;
      n[t * 3 + 1] = vh ? row[0] : 0.f;
      n[t * 3 + 2] = (vh && vE) ? row[1] : 0.f;
    }
    float rs0 = n[0] + n[1] + n[2];
    float rs1 = n[3] + n[4] + n[5];
    float rs2 = n[6] + n[7] + n[8];
    float rs3 = n[9] + n[10] + n[11];
    float ap0 = (rs0 + rs1 + rs2) * (1.f / 9.f);
    float ap1 = (rs1 + rs2 + rs3) * (1.f / 9.f);

    float aw[12], ab[12];
    *(float4*)&aw[0] = *(const float4*)&mp[icg * 24];
    *(float4*)&aw[4] = *(const float4*)&mp[icg * 24 + 4];
    *(float4*)&aw[8] = *(const float4*)&mp[icg * 24 + 8];
    *(float4*)&ab[0] = *(const float4*)&mp[icg * 24 + 12];
    *(float4*)&ab[4] = *(const float4*)&mp[icg * 24 + 16];
    *(float4*)&ab[8] = *(const float4*)&mp[icg * 24 + 20];

    float f0[9], f1[9], a0[9], a1[9];
    float amax0 = -1e30f, amax1 = -1e30f;
#pragma unroll
    for (int j = 0; j < 9; ++j) {
      float wt[12];
      *(float4*)&wt[0] = *(const float4*)&scwp[icg * 108 + j * 12];
      *(float4*)&wt[4] = *(const float4*)&scwp[icg * 108 + j * 12 + 4];
      *(float4*)&wt[8] = *(const float4*)&scwp[icg * 108 + j * 12 + 8];
      float p0 = wt[9], p1 = wt[9];
#pragma unroll
      for (int t = 0; t < 9; ++t) {
        p0 = fmaf(n[t], wt[t], p0);       // rows 0..2
        p1 = fmaf(n[t + 3], wt[t], p1);   // rows 1..3
      }
      f0[j] = silu_f(p0);
      f1[j] = silu_f(p1);
      float v0 = fmaf(ap0, aw[j], ab[j]);
      float v1 = fmaf(ap1, aw[j], ab[j]);
      a0[j] = v0; a1[j] = v1;
      amax0 = fmaxf(amax0, v0);
      amax1 = fmaxf(amax1, v1);
    }
    float es0 = 0.f, es1 = 0.f;
    float p0[9], p1[9];
#pragma unroll
    for (int j = 0; j < 9; ++j) {
      float e0 = __expf(a0[j] - amax0);
      float e1 = __expf(a1[j] - amax1);
      es0 += e0; es1 += e1;
      p0[j] = f0[j] * e0;
      p1[j] = f1[j] * e1;
    }
    float i0 = __fdividef(1.f, es0);
    float i1 = __fdividef(1.f, es1);
#pragma unroll
    for (int j = 0; j < 9; ++j) { p0[j] *= i0; p1[j] *= i1; }

#pragma unroll
    for (int oco = 0; oco < 16; ++oco) {
      float ov[12];
      *(float4*)&ov[0] = *(const float4*)&ocwp[icg * 192 + oco * 12];
      *(float4*)&ov[4] = *(const float4*)&ocwp[icg * 192 + oco * 12 + 4];
      *(float4*)&ov[8] = *(const float4*)&ocwp[icg * 192 + oco * 12 + 8];
      float s0 = 0.f, s1 = 0.f;
#pragma unroll
      for (int j = 0; j < 9; ++j) {
        s0 = fmaf(p0[j], ov[j], s0);
        s1 = fmaf(p1[j], ov[j], s1);
      }
      acc0[oco] += s0;
      acc1[oco] += s1;
    }
  }

  // ---- merge: waves !=0 add row-0 partials, waves !=1 add row-1 partials ----
  if (wv != 0) {
    float* rp = &mbuf[lane * 33];
#pragma unroll
    for (int k = 0; k < 16; ++k) atomicAdd(&rp[k], acc0[k]);
  }
  if (wv != 1) {
    float* rp = &mbuf[(64 + lane) * 33];
#pragma unroll
    for (int k = 0; k < 16; ++k) atomicAdd(&rp[k], acc1[k]);
  }
  __syncthreads();

  if (wv < 2) {
    float av[16];
    if (wv == 0) {
      const float* rp = &mbuf[lane * 33];
#pragma unroll
      for (int k = 0; k < 16; ++k) av[k] = acc0[k] + rp[k];
    } else {
      const float* rp = &mbuf[(64 + lane) * 33];
#pragma unroll
      for (int k = 0; k < 16; ++k) av[k] = acc1[k] + rp[k];
    }
    float* op = xrfa + ((size_t)(b * 64 + g * 16)) * 4096 + (r0 + wv) * 64 + w;
#pragma unroll
    for (int oco = 0; oco < 16; ++oco) {
      int oc = g * 16 + oco;
      float s = bn_g[oc] * rsqrtf(bn_v[oc] + EPS);
      float bb = bn_b[oc] - bn_m[oc] * s;
      float v = fmaf(av[oco] + oc_b[oc], s, bb);
      op[oco * 4096] = silu_f(v);
    }
  }
}

// ---------------------------------------------------------------------------
// Kernel D: final 1x1 conv + BN + SiLU (R5 oc-split, unchanged).
// ---------------------------------------------------------------------------
__global__ __launch_bounds__(256) void k_fuse(
    const float* __restrict__ x, const float* __restrict__ xrfa,
    const float* __restrict__ s2, const float* __restrict__ fu_w,
    const float* __restrict__ fu_b, const float* __restrict__ bn_g,
    const float* __restrict__ bn_b, const float* __restrict__ bn_m,
    const float* __restrict__ bn_v, float* __restrict__ out) {
  __shared__ __align__(16) float fw[4096];
  __shared__ float s2l[64];
  const int blk = blockIdx.x;          // 512 blocks
  const int tid = threadIdx.x;
  const int sloc = tid & 63;
  const int ocq = tid >> 6;            // oc octet 0..3
  const int b = blk >> 6;
  const int sp = (blk & 63) * 64 + sloc;

  for (int i = tid; i < 1024; i += 256)
    ((float4*)fw)[i] = ((const float4*)fu_w)[i];
  if (tid < 64) s2l[tid] = s2[b * 64 + tid];

  const float* xr = xrfa + (size_t)b * 64 * 4096 + sp;
  const float* xp = x + (size_t)b * 64 * 4096 + sp;
  float va[64], vb[64];
#pragma unroll
  for (int i = 0; i < 64; ++i) va[i] = xr[i * 4096];
#pragma unroll
  for (int i = 0; i < 64; ++i) vb[i] = xp[i * 4096];
  __syncthreads();
#pragma unroll
  for (int i = 0; i < 64; ++i) vb[i] *= s2l[i];

  float* op = out + (size_t)b * 32 * 4096 + sp;
#pragma unroll 1
  for (int o = 0; o < 8; ++o) {
    const int oc = ocq * 8 + o;
    const float* wr = &fw[oc * 128];
    float a = 0.f;
#pragma unroll
    for (int q = 0; q < 16; ++q) {
      float4 w4 = *(const float4*)&wr[q * 4];
      a = fmaf(va[q * 4 + 0], w4.x, a);
      a = fmaf(va[q * 4 + 1], w4.y, a);
      a = fmaf(va[q * 4 + 2], w4.z, a);
      a = fmaf(va[q * 4 + 3], w4.w, a);
    }
#pragma unroll
    for (int q = 0; q < 16; ++q) {
      float4 w4 = *(const float4*)&wr[64 + q * 4];
      a = fmaf(vb[q * 4 + 0], w4.x, a);
      a = fmaf(vb[q * 4 + 1], w4.y, a);
      a = fmaf(vb[q * 4 + 2], w4.z, a);
      a = fmaf(vb[q * 4 + 3], w4.w, a);
    }
    float s = bn_g[oc] * rsqrtf(bn_v[oc] + EPS);
    float v = a + fu_b[oc];
    v = fmaf(v, s, bn_b[oc] - bn_m[oc] * s);
    op[oc * 4096] = silu_f(v);
  }
}

extern "C" void kernel_launch(void* const* d_in, const int* in_sizes, int n_in,
                              void* d_out, int out_size, void* d_ws, size_t ws_size,
                              hipStream_t stream) {
  const float* x       = (const float*)d_in[0];
  const float* sc_w    = (const float*)d_in[1];
  const float* sc_b    = (const float*)d_in[2];
  const float* ac_w    = (const float*)d_in[3];
  const float* ac_b    = (const float*)d_in[4];
  const float* oc_w    = (const float*)d_in[5];
  const float* oc_b    = (const float*)d_in[6];
  const float* oc_bn_g = (const float*)d_in[7];
  const float* oc_bn_b = (const float*)d_in[8];
  const float* oc_bn_m = (const float*)d_in[9];
  const float* oc_bn_v = (const float*)d_in[10];
  const float* ex_w    = (const float*)d_in[11];
  const float* ey_w    = (const float*)d_in[12];
  const float* ez_w    = (const float*)d_in[13];
  const float* ff_w    = (const float*)d_in[14];
  const float* ff_b    = (const float*)d_in[15];
  const float* g1_w    = (const float*)d_in[16];
  const float* g1_b    = (const float*)d_in[17];
  const float* g2_w    = (const float*)d_in[18];
  const float* g2_b    = (const float*)d_in[19];
  const float* fu_w    = (const float*)d_in[20];
  const float* fu_b    = (const float*)d_in[21];
  const float* fu_bn_g = (const float*)d_in[22];
  const float* fu_bn_b = (const float*)d_in[23];
  const float* fu_bn_m = (const float*)d_in[24];
  const float* fu_bn_v = (const float*)d_in[25];

  float* ws     = (float*)d_ws;
  float* energy = ws;            // 512 floats
  float* meanx  = ws + 512;      // 512 floats
  float* s2     = ws + 1024;     // 512 floats
  float* xrfa   = ws + 2048;     // 8*64*4096 floats

  k_dft<<<512, 256, 0, stream>>>(x, energy, meanx);
  k_attn<<<8, 64, 0, stream>>>(energy, meanx, ex_w, ey_w, ez_w,
                               ff_w, ff_b, g1_w, g1_b, g2_w, g2_b, s2);
  k_rfa<<<1024, 256, 0, stream>>>(x, sc_w, sc_b, ac_w, ac_b, oc_w, oc_b,
                                  oc_bn_g, oc_bn_b, oc_bn_m, oc_bn_v, xrfa);
  k_fuse<<<512, 256, 0, stream>>>(x, xrfa, s2, fu_w, fu_b,
                                  fu_bn_g, fu_bn_b, fu_bn_m, fu_bn_v,
                                  (float*)d_out);
}

// Round 9
// 172.133 us; speedup vs baseline: 1.1659x; 1.1659x over previous
//
#include <hip/hip_runtime.h>
#include <math.h>

#define EPS 1e-5f

__device__ __forceinline__ float wave_sum(float v) {
  v += __shfl_down(v, 32);
  v += __shfl_down(v, 16);
  v += __shfl_down(v, 8);
  v += __shfl_down(v, 4);
  v += __shfl_down(v, 2);
  v += __shfl_down(v, 1);
  return v;
}

__device__ __forceinline__ float silu_f(float v) { return v / (1.f + __expf(-v)); }
__device__ __forceinline__ float sigm_f(float v) { return 1.f / (1.f + __expf(-v)); }

__device__ __forceinline__ unsigned bf16r(float v) {   // RNE fp32 -> bf16 bits
  unsigned u = __float_as_uint(v);
  return (u + 0x7FFFu + ((u >> 16) & 1u)) >> 16;
}

__device__ __forceinline__ int bitrev6(int v) {
  return ((v & 1) << 5) | ((v & 2) << 3) | ((v & 4) << 1) |
         ((v & 8) >> 1) | ((v & 16) >> 3) | ((v & 32) >> 5);
}

#define FFT6(zr, zi)                                           \
  do {                                                         \
    _Pragma("unroll") for (int s = 0; s < 6; ++s) {            \
      const int half = 32 >> s;                                \
      const bool up = (lane & half) != 0;                      \
      float pr = __shfl_xor(zr, half);                         \
      float pi = __shfl_xor(zi, half);                         \
      float tr = up ? pr - zr : zr + pr;                       \
      float ti = up ? pi - zi : zi + pi;                       \
      const float c = twc[s], sn = tws[s];                     \
      zr = tr * c - ti * sn;                                   \
      zi = tr * sn + ti * c;                                   \
    }                                                          \
  } while (0)

// ---------------------------------------------------------------------------
// Kernel A: per-(b,c) mean |2D-DFT| + spatial mean (R5 version).
// ---------------------------------------------------------------------------
__global__ __launch_bounds__(256) void k_dft(const float* __restrict__ x,
                                             float* __restrict__ energy,
                                             float* __restrict__ meanx) {
  __shared__ float re1[33 * 65];   // [kv 0..32][h]
  __shared__ float im1[33 * 65];
  __shared__ float redA[4], redB[4];
  const int bc = blockIdx.x;       // b*64 + c
  const int tid = threadIdx.x;
  const int lane = tid & 63;
  const int wv = tid >> 6;         // wave 0..3
  const float* xp = x + (size_t)bc * 4096;

  float twc[6], tws[6];
#pragma unroll
  for (int s = 0; s < 6; ++s) {
    int half = 32 >> s;
    if (lane & half) {
      float ang = -6.283185307179586f * (float)((lane & (half - 1)) << s) / 64.f;
      float sv, cv;
      __sincosf(ang, &sv, &cv);
      twc[s] = cv;
      tws[s] = sv;
    } else {
      twc[s] = 1.f;
      tws[s] = 0.f;
    }
  }

  const int f = bitrev6(lane);
  const int fm = (64 - f) & 63;
  const int plane = bitrev6(fm);

  float lsum = 0.f;
#pragma unroll 1
  for (int rp = 0; rp < 4; ++rp) {
    const int h0 = wv * 16 + rp * 4;
    float x0 = xp[h0 * 64 + lane];
    float x1 = xp[(h0 + 1) * 64 + lane];
    float x2 = xp[(h0 + 2) * 64 + lane];
    float x3 = xp[(h0 + 3) * 64 + lane];
    lsum += x0 + x1 + x2 + x3;
    float zr = x0, zi = x1, yr = x2, yi = x3;
#pragma unroll
    for (int s = 0; s < 6; ++s) {
      const int half = 32 >> s;
      const bool up = (lane & half) != 0;
      float pzr = __shfl_xor(zr, half);
      float pzi = __shfl_xor(zi, half);
      float pyr = __shfl_xor(yr, half);
      float pyi = __shfl_xor(yi, half);
      float tzr = up ? pzr - zr : zr + pzr;
      float tzi = up ? pzi - zi : zi + pzi;
      float tyr = up ? pyr - yr : yr + pyr;
      float tyi = up ? pyi - yi : yi + pyi;
      const float c = twc[s], sn = tws[s];
      zr = tzr * c - tzi * sn;
      zi = tzr * sn + tzi * c;
      yr = tyr * c - tyi * sn;
      yi = tyr * sn + tyi * c;
    }
    float mzr = __shfl(zr, plane), mzi = __shfl(zi, plane);
    float myr = __shfl(yr, plane), myi = __shfl(yi, plane);
    if (f <= 32) {
      float ar = 0.5f * (zr + mzr), ai = 0.5f * (zi - mzi);
      float br = 0.5f * (zi + mzi), bi = 0.5f * (mzr - zr);
      float cr = 0.5f * (yr + myr), ci = 0.5f * (yi - myi);
      float dr = 0.5f * (yi + myi), di = 0.5f * (myr - yr);
      re1[f * 65 + h0] = ar;     im1[f * 65 + h0] = ai;
      re1[f * 65 + h0 + 1] = br; im1[f * 65 + h0 + 1] = bi;
      re1[f * 65 + h0 + 2] = cr; im1[f * 65 + h0 + 2] = ci;
      re1[f * 65 + h0 + 3] = dr; im1[f * 65 + h0 + 3] = di;
    }
  }
  __syncthreads();

  float msum = 0.f;
#pragma unroll 1
  for (int i = 0; i < 4; ++i) {
    const int kv1 = wv + 8 * i;
    const int kv2 = kv1 + 4;
    const float w1 = (kv1 == 0) ? 1.f : 2.f;
    float ar = re1[kv1 * 65 + lane];
    float ai = im1[kv1 * 65 + lane];
    float br = re1[kv2 * 65 + lane];
    float bi = im1[kv2 * 65 + lane];
#pragma unroll
    for (int s = 0; s < 6; ++s) {
      const int half = 32 >> s;
      const bool up = (lane & half) != 0;
      float par = __shfl_xor(ar, half);
      float pai = __shfl_xor(ai, half);
      float pbr = __shfl_xor(br, half);
      float pbi = __shfl_xor(bi, half);
      float tar = up ? par - ar : ar + par;
      float tai = up ? pai - ai : ai + pai;
      float tbr = up ? pbr - br : br + pbr;
      float tbi = up ? pbi - bi : bi + pbi;
      const float c = twc[s], sn = tws[s];
      ar = tar * c - tai * sn;
      ai = tar * sn + tai * c;
      br = tbr * c - tbi * sn;
      bi = tbr * sn + tbi * c;
    }
    msum += w1 * sqrtf(ar * ar + ai * ai) + 2.f * sqrtf(br * br + bi * bi);
  }
  if (wv == 0) {
    float ar = re1[32 * 65 + lane];
    float ai = im1[32 * 65 + lane];
    FFT6(ar, ai);
    msum += sqrtf(ar * ar + ai * ai);
  }

  msum = wave_sum(msum);
  lsum = wave_sum(lsum);
  if (lane == 0) { redA[wv] = msum; redB[wv] = lsum; }
  __syncthreads();
  if (tid == 0) {
    float e = redA[0] + redA[1] + redA[2] + redA[3];
    float m = redB[0] + redB[1] + redB[2] + redB[3];
    energy[bc] = e * (1.f / 4096.f);
    meanx[bc] = m * (1.f / 4096.f);
  }
}

// ---------------------------------------------------------------------------
// Kernel B: per-batch channel attention head (unchanged).
// ---------------------------------------------------------------------------
__global__ __launch_bounds__(64) void k_attn(
    const float* __restrict__ energy, const float* __restrict__ meanx,
    const float* __restrict__ ex_w, const float* __restrict__ ey_w,
    const float* __restrict__ ez_w, const float* __restrict__ ff_w,
    const float* __restrict__ ff_b, const float* __restrict__ g1_w,
    const float* __restrict__ g1_b, const float* __restrict__ g2_w,
    const float* __restrict__ g2_b, float* __restrict__ s2) {
  __shared__ float e[64], mx[64], my[64], mz[64];
  __shared__ float ax[64], ay[64], az[64], af[64], h1[16];
  const int b = blockIdx.x;
  const int c = threadIdx.x;
  e[c] = energy[b * 64 + c];
  mx[c] = meanx[b * 64 + c];
  __syncthreads();
  int rank = 0;
  float ec = e[c];
  for (int i = 0; i < 64; ++i) {
    float ei = e[i];
    rank += (ei > ec) || (ei == ec && i < c);
  }
  float mask = (rank < 32) ? 1.f : 0.f;
  my[c] = mx[c] * mask;
  mz[c] = mx[c] * (1.f - mask);
  __syncthreads();
  {
    float l, r, m;
    l = (c > 0) ? mx[c - 1] : 0.f; m = mx[c]; r = (c < 63) ? mx[c + 1] : 0.f;
    ax[c] = sigm_f(ex_w[0] * l + ex_w[1] * m + ex_w[2] * r);
    l = (c > 0) ? my[c - 1] : 0.f; m = my[c]; r = (c < 63) ? my[c + 1] : 0.f;
    ay[c] = sigm_f(ey_w[0] * l + ey_w[1] * m + ey_w[2] * r);
    l = (c > 0) ? mz[c - 1] : 0.f; m = mz[c]; r = (c < 63) ? mz[c + 1] : 0.f;
    az[c] = sigm_f(ez_w[0] * l + ez_w[1] * m + ez_w[2] * r);
  }
  __syncthreads();
  {
    int g = c >> 4;
    float acc = ff_b[c];
#pragma unroll
    for (int i = 0; i < 32; ++i) {
      int ch = g * 32 + i;
      float v = (ch < 64) ? ay[ch] : az[ch - 64];
      acc = fmaf(v, ff_w[c * 32 + i], acc);
    }
    af[c] = acc;
  }
  __syncthreads();
  if (c < 16) {
    float a = g1_b[c];
#pragma unroll
    for (int i = 0; i < 64; ++i) a = fmaf(af[i], g1_w[c * 128 + i], a);
#pragma unroll
    for (int i = 0; i < 64; ++i) a = fmaf(ax[i], g1_w[c * 128 + 64 + i], a);
    h1[c] = silu_f(a);
  }
  __syncthreads();
  float gv = g2_b[c];
#pragma unroll
  for (int o = 0; o < 16; ++o) gv = fmaf(h1[o], g2_w[c * 16 + o], gv);
  gv = sigm_f(gv);
  s2[b * 64 + c] = gv * af[c] + (1.f - gv) * ax[c];
}

// ---------------------------------------------------------------------------
// Kernel C: fused ReceptiveFieldAttentionConv.
// R8 = exact R5 structure (512 blocks, icg-split-2, P=2, 46 us proven) with
// ONE change: oc-conv weights packed as bf16 PAIRS (oco even|odd in one
// uint) -> the oc phase reads 24 b128/icg instead of 48, shifting ~8 us of
// LDS-pipe time onto the VALU's measured 44% slack (2 unpack VALU per uint).
// ---------------------------------------------------------------------------
__global__ __launch_bounds__(256) void k_rfa(
    const float* __restrict__ x,
    const float* __restrict__ sc_w, const float* __restrict__ sc_b,
    const float* __restrict__ ac_w, const float* __restrict__ ac_b,
    const float* __restrict__ oc_w, const float* __restrict__ oc_b,
    const float* __restrict__ bn_g, const float* __restrict__ bn_b,
    const float* __restrict__ bn_m, const float* __restrict__ bn_v,
    float* __restrict__ xrfa) {
  __shared__ __align__(16) float scwp[16 * 9 * 12];     // taps 0..8, bias at [9]
  __shared__ __align__(16) float mp[16 * 24];           // acw [0..8], acb [12..20]
  __shared__ __align__(16) unsigned ocwb[16 * 8 * 12];  // bf16 pair-packed
  __shared__ float red[128 * 33];                       // icg-half merge
  const int blk = blockIdx.x;          // 512 blocks: 16 bands x 4 g x 8 b
  const int band = blk & 15;
  const int g = (blk >> 4) & 3;
  const int b = blk >> 6;
  const int tid = threadIdx.x;
  const int lane = tid & 63;
  const int wv = tid >> 6;             // 0..3
  const int wp = wv & 1;               // row-pair within band
  const int half = wv >> 1;            // icg half

  // ---- stage packed weights ----
  for (int i = tid; i < 1296; i += 256) {
    int icg = i / 81, rem = i - icg * 81;
    int j = rem / 9, t = rem - j * 9;
    scwp[icg * 108 + j * 12 + t] = sc_w[(g * 144 + icg * 9 + j) * 9 + t];
  }
  if (tid < 144) {
    int icg = tid / 9, j = tid - icg * 9;
    scwp[icg * 108 + j * 12 + 9] = sc_b[g * 144 + tid];
    mp[icg * 24 + j] = ac_w[g * 144 + tid];
    mp[icg * 24 + 12 + j] = ac_b[g * 144 + tid];
  }
  // oc weights: for icg, oco-pair o2, tap j: u = bf16(W[2*o2][j]) | bf16(W[2*o2+1][j])<<16
  for (int i = tid; i < 1152; i += 256) {
    int icg = i / 72, rem = i - icg * 72;
    int o2 = rem / 9, j = rem - o2 * 9;
    float w0 = oc_w[((g * 16 + 2 * o2) * 16 + icg) * 9 + j];
    float w1 = oc_w[((g * 16 + 2 * o2 + 1) * 16 + icg) * 9 + j];
    ocwb[icg * 96 + o2 * 12 + j] = bf16r(w0) | (bf16r(w1) << 16);
  }
  __syncthreads();

  const int r0 = band * 4 + wp * 2;
  const int w = lane;
  const bool vW = w > 0, vE = w < 63;
  float acc0[16], acc1[16];
#pragma unroll
  for (int i = 0; i < 16; ++i) { acc0[i] = 0.f; acc1[i] = 0.f; }

  const float* xg = x + ((size_t)(b * 64 + g * 16)) * 4096 + w;
  const int icg0 = half * 8;

#pragma unroll 1
  for (int ii = 0; ii < 8; ++ii) {
    const int icg = icg0 + ii;
    const float* xc = xg + icg * 4096;
    float n[12];
#pragma unroll
    for (int t = 0; t < 4; ++t) {
      int h = r0 - 1 + t;
      bool vh = (h >= 0) && (h < 64);
      const float* row = xc + h * 64;
      n[t * 3 + 0] = (vh && vW) ? row[-1] : 0.f;
      n[t * 3 + 1] = vh ? row[0] : 0.f;
      n[t * 3 + 2] = (vh && vE) ? row[1] : 0.f;
    }
    float rs0 = n[0] + n[1] + n[2];
    float rs1 = n[3] + n[4] + n[5];
    float rs2 = n[6] + n[7] + n[8];
    float rs3 = n[9] + n[10] + n[11];
    float ap0 = (rs0 + rs1 + rs2) * (1.f / 9.f);
    float ap1 = (rs1 + rs2 + rs3) * (1.f / 9.f);

    float aw[12], ab[12];
    *(float4*)&aw[0] = *(const float4*)&mp[icg * 24];
    *(float4*)&aw[4] = *(const float4*)&mp[icg * 24 + 4];
    *(float4*)&aw[8] = *(const float4*)&mp[icg * 24 + 8];
    *(float4*)&ab[0] = *(const float4*)&mp[icg * 24 + 12];
    *(float4*)&ab[4] = *(const float4*)&mp[icg * 24 + 16];
    *(float4*)&ab[8] = *(const float4*)&mp[icg * 24 + 20];

    float f0[9], f1[9], a0[9], a1[9];
    float amax0 = -1e30f, amax1 = -1e30f;
#pragma unroll
    for (int j = 0; j < 9; ++j) {
      float wt[12];
      *(float4*)&wt[0] = *(const float4*)&scwp[icg * 108 + j * 12];
      *(float4*)&wt[4] = *(const float4*)&scwp[icg * 108 + j * 12 + 4];
      *(float4*)&wt[8] = *(const float4*)&scwp[icg * 108 + j * 12 + 8];
      float p0 = wt[9], p1 = wt[9];
#pragma unroll
      for (int t = 0; t < 9; ++t) {
        p0 = fmaf(n[t], wt[t], p0);       // rows 0..2
        p1 = fmaf(n[t + 3], wt[t], p1);   // rows 1..3
      }
      f0[j] = silu_f(p0);
      f1[j] = silu_f(p1);
      float v0 = fmaf(ap0, aw[j], ab[j]);
      float v1 = fmaf(ap1, aw[j], ab[j]);
      a0[j] = v0; a1[j] = v1;
      amax0 = fmaxf(amax0, v0);
      amax1 = fmaxf(amax1, v1);
    }
    float es0 = 0.f, es1 = 0.f;
    float p0[9], p1[9];
#pragma unroll
    for (int j = 0; j < 9; ++j) {
      float e0 = __expf(a0[j] - amax0);
      float e1 = __expf(a1[j] - amax1);
      es0 += e0; es1 += e1;
      p0[j] = f0[j] * e0;
      p1[j] = f1[j] * e1;
    }
    float i0 = __fdividef(1.f, es0);
    float i1 = __fdividef(1.f, es1);
#pragma unroll
    for (int j = 0; j < 9; ++j) { p0[j] *= i0; p1[j] *= i1; }

    // oc phase: bf16 pair-packed weights, 3 b128 per oco-PAIR
#pragma unroll
    for (int o2 = 0; o2 < 8; ++o2) {
      unsigned u[12];
      *(uint4*)&u[0] = *(const uint4*)&ocwb[icg * 96 + o2 * 12];
      *(uint4*)&u[4] = *(const uint4*)&ocwb[icg * 96 + o2 * 12 + 4];
      *(uint4*)&u[8] = *(const uint4*)&ocwb[icg * 96 + o2 * 12 + 8];
      float se0 = 0.f, so0 = 0.f, se1 = 0.f, so1 = 0.f;
#pragma unroll
      for (int j = 0; j < 9; ++j) {
        float we = __uint_as_float(u[j] << 16);          // oco even
        float wo = __uint_as_float(u[j] & 0xFFFF0000u);  // oco odd
        se0 = fmaf(p0[j], we, se0);
        so0 = fmaf(p0[j], wo, so0);
        se1 = fmaf(p1[j], we, se1);
        so1 = fmaf(p1[j], wo, so1);
      }
      acc0[2 * o2] += se0;
      acc0[2 * o2 + 1] += so0;
      acc1[2 * o2] += se1;
      acc1[2 * o2 + 1] += so1;
    }
  }

  // ---- merge the two icg halves (stride-33: banks (rid+k)%32, free) ----
  const int rid = wp * 64 + lane;
  if (half == 1) {
#pragma unroll
    for (int k = 0; k < 16; ++k) {
      red[rid * 33 + k] = acc0[k];
      red[rid * 33 + 16 + k] = acc1[k];
    }
  }
  __syncthreads();
  if (half == 0) {
#pragma unroll
    for (int k = 0; k < 16; ++k) {
      acc0[k] += red[rid * 33 + k];
      acc1[k] += red[rid * 33 + 16 + k];
    }
    float* op = xrfa + ((size_t)(b * 64 + g * 16)) * 4096 + r0 * 64 + w;
#pragma unroll
    for (int oco = 0; oco < 16; ++oco) {
      int oc = g * 16 + oco;
      float s = bn_g[oc] * rsqrtf(bn_v[oc] + EPS);
      float bb = bn_b[oc] - bn_m[oc] * s;
      float ob = oc_b[oc];
      float v0 = fmaf(acc0[oco] + ob, s, bb);
      float v1 = fmaf(acc1[oco] + ob, s, bb);
      op[oco * 4096] = silu_f(v0);
      op[oco * 4096 + 64] = silu_f(v1);
    }
  }
}

// ---------------------------------------------------------------------------
// Kernel D: final 1x1 conv + BN + SiLU (R5 oc-split, unchanged).
// ---------------------------------------------------------------------------
__global__ __launch_bounds__(256) void k_fuse(
    const float* __restrict__ x, const float* __restrict__ xrfa,
    const float* __restrict__ s2, const float* __restrict__ fu_w,
    const float* __restrict__ fu_b, const float* __restrict__ bn_g,
    const float* __restrict__ bn_b, const float* __restrict__ bn_m,
    const float* __restrict__ bn_v, float* __restrict__ out) {
  __shared__ __align__(16) float fw[4096];
  __shared__ float s2l[64];
  const int blk = blockIdx.x;          // 512 blocks
  const int tid = threadIdx.x;
  const int sloc = tid & 63;
  const int ocq = tid >> 6;            // oc octet 0..3
  const int b = blk >> 6;
  const int sp = (blk & 63) * 64 + sloc;

  for (int i = tid; i < 1024; i += 256)
    ((float4*)fw)[i] = ((const float4*)fu_w)[i];
  if (tid < 64) s2l[tid] = s2[b * 64 + tid];

  const float* xr = xrfa + (size_t)b * 64 * 4096 + sp;
  const float* xp = x + (size_t)b * 64 * 4096 + sp;
  float va[64], vb[64];
#pragma unroll
  for (int i = 0; i < 64; ++i) va[i] = xr[i * 4096];
#pragma unroll
  for (int i = 0; i < 64; ++i) vb[i] = xp[i * 4096];
  __syncthreads();
#pragma unroll
  for (int i = 0; i < 64; ++i) vb[i] *= s2l[i];

  float* op = out + (size_t)b * 32 * 4096 + sp;
#pragma unroll 1
  for (int o = 0; o < 8; ++o) {
    const int oc = ocq * 8 + o;
    const float* wr = &fw[oc * 128];
    float a = 0.f;
#pragma unroll
    for (int q = 0; q < 16; ++q) {
      float4 w4 = *(const float4*)&wr[q * 4];
      a = fmaf(va[q * 4 + 0], w4.x, a);
      a = fmaf(va[q * 4 + 1], w4.y, a);
      a = fmaf(va[q * 4 + 2], w4.z, a);
      a = fmaf(va[q * 4 + 3], w4.w, a);
    }
#pragma unroll
    for (int q = 0; q < 16; ++q) {
      float4 w4 = *(const float4*)&wr[64 + q * 4];
      a = fmaf(vb[q * 4 + 0], w4.x, a);
      a = fmaf(vb[q * 4 + 1], w4.y, a);
      a = fmaf(vb[q * 4 + 2], w4.z, a);
      a = fmaf(vb[q * 4 + 3], w4.w, a);
    }
    float s = bn_g[oc] * rsqrtf(bn_v[oc] + EPS);
    float v = a + fu_b[oc];
    v = fmaf(v, s, bn_b[oc] - bn_m[oc] * s);
    op[oc * 4096] = silu_f(v);
  }
}

extern "C" void kernel_launch(void* const* d_in, const int* in_sizes, int n_in,
                              void* d_out, int out_size, void* d_ws, size_t ws_size,
                              hipStream_t stream) {
  const float* x       = (const float*)d_in[0];
  const float* sc_w    = (const float*)d_in[1];
  const float* sc_b    = (const float*)d_in[2];
  const float* ac_w    = (const float*)d_in[3];
  const float* ac_b    = (const float*)d_in[4];
  const float* oc_w    = (const float*)d_in[5];
  const float* oc_b    = (const float*)d_in[6];
  const float* oc_bn_g = (const float*)d_in[7];
  const float* oc_bn_b = (const float*)d_in[8];
  const float* oc_bn_m = (const float*)d_in[9];
  const float* oc_bn_v = (const float*)d_in[10];
  const float* ex_w    = (const float*)d_in[11];
  const float* ey_w    = (const float*)d_in[12];
  const float* ez_w    = (const float*)d_in[13];
  const float* ff_w    = (const float*)d_in[14];
  const float* ff_b    = (const float*)d_in[15];
  const float* g1_w    = (const float*)d_in[16];
  const float* g1_b    = (const float*)d_in[17];
  const float* g2_w    = (const float*)d_in[18];
  const float* g2_b    = (const float*)d_in[19];
  const float* fu_w    = (const float*)d_in[20];
  const float* fu_b    = (const float*)d_in[21];
  const float* fu_bn_g = (const float*)d_in[22];
  const float* fu_bn_b = (const float*)d_in[23];
  const float* fu_bn_m = (const float*)d_in[24];
  const float* fu_bn_v = (const float*)d_in[25];

  float* ws     = (float*)d_ws;
  float* energy = ws;            // 512 floats
  float* meanx  = ws + 512;      // 512 floats
  float* s2     = ws + 1024;     // 512 floats
  float* xrfa   = ws + 2048;     // 8*64*4096 floats

  k_dft<<<512, 256, 0, stream>>>(x, energy, meanx);
  k_attn<<<8, 64, 0, stream>>>(energy, meanx, ex_w, ey_w, ez_w,
                               ff_w, ff_b, g1_w, g1_b, g2_w, g2_b, s2);
  k_rfa<<<512, 256, 0, stream>>>(x, sc_w, sc_b, ac_w, ac_b, oc_w, oc_b,
                                 oc_bn_g, oc_bn_b, oc_bn_m, oc_bn_v, xrfa);
  k_fuse<<<512, 256, 0, stream>>>(x, xrfa, s2, fu_w, fu_b,
                                  fu_bn_g, fu_bn_b, fu_bn_m, fu_bn_v,
                                  (float*)d_out);
}

// Round 10
// 168.767 us; speedup vs baseline: 1.1891x; 1.0199x over previous
//
#include <hip/hip_runtime.h>
#include <math.h>

#define EPS 1e-5f

__device__ __forceinline__ float wave_sum(float v) {
  v += __shfl_down(v, 32);
  v += __shfl_down(v, 16);
  v += __shfl_down(v, 8);
  v += __shfl_down(v, 4);
  v += __shfl_down(v, 2);
  v += __shfl_down(v, 1);
  return v;
}

// fast reciprocal (v_rcp_f32, ~1 ulp) — avoids the ~10-instr IEEE div sequence
__device__ __forceinline__ float frcp(float x) { return __builtin_amdgcn_rcpf(x); }
__device__ __forceinline__ float silu_f(float v) { return v * frcp(1.f + __expf(-v)); }
__device__ __forceinline__ float sigm_f(float v) { return frcp(1.f + __expf(-v)); }

__device__ __forceinline__ unsigned bf16r(float v) {   // RNE fp32 -> bf16 bits
  unsigned u = __float_as_uint(v);
  return (u + 0x7FFFu + ((u >> 16) & 1u)) >> 16;
}

__device__ __forceinline__ int bitrev6(int v) {
  return ((v & 1) << 5) | ((v & 2) << 3) | ((v & 4) << 1) |
         ((v & 8) >> 1) | ((v & 16) >> 3) | ((v & 32) >> 5);
}

#define FFT6(zr, zi)                                           \
  do {                                                         \
    _Pragma("unroll") for (int s = 0; s < 6; ++s) {            \
      const int half = 32 >> s;                                \
      const bool up = (lane & half) != 0;                      \
      float pr = __shfl_xor(zr, half);                         \
      float pi = __shfl_xor(zi, half);                         \
      float tr = up ? pr - zr : zr + pr;                       \
      float ti = up ? pi - zi : zi + pi;                       \
      const float c = twc[s], sn = tws[s];                     \
      zr = tr * c - ti * sn;                                   \
      zi = tr * sn + ti * c;                                   \
    }                                                          \
  } while (0)

// ---------------------------------------------------------------------------
// Kernel A: per-(b,c) mean |2D-DFT| + spatial mean (R5 version).
// ---------------------------------------------------------------------------
__global__ __launch_bounds__(256) void k_dft(const float* __restrict__ x,
                                             float* __restrict__ energy,
                                             float* __restrict__ meanx) {
  __shared__ float re1[33 * 65];   // [kv 0..32][h]
  __shared__ float im1[33 * 65];
  __shared__ float redA[4], redB[4];
  const int bc = blockIdx.x;       // b*64 + c
  const int tid = threadIdx.x;
  const int lane = tid & 63;
  const int wv = tid >> 6;         // wave 0..3
  const float* xp = x + (size_t)bc * 4096;

  float twc[6], tws[6];
#pragma unroll
  for (int s = 0; s < 6; ++s) {
    int half = 32 >> s;
    if (lane & half) {
      float ang = -6.283185307179586f * (float)((lane & (half - 1)) << s) / 64.f;
      float sv, cv;
      __sincosf(ang, &sv, &cv);
      twc[s] = cv;
      tws[s] = sv;
    } else {
      twc[s] = 1.f;
      tws[s] = 0.f;
    }
  }

  const int f = bitrev6(lane);
  const int fm = (64 - f) & 63;
  const int plane = bitrev6(fm);

  float lsum = 0.f;
#pragma unroll 1
  for (int rp = 0; rp < 4; ++rp) {
    const int h0 = wv * 16 + rp * 4;
    float x0 = xp[h0 * 64 + lane];
    float x1 = xp[(h0 + 1) * 64 + lane];
    float x2 = xp[(h0 + 2) * 64 + lane];
    float x3 = xp[(h0 + 3) * 64 + lane];
    lsum += x0 + x1 + x2 + x3;
    float zr = x0, zi = x1, yr = x2, yi = x3;
#pragma unroll
    for (int s = 0; s < 6; ++s) {
      const int half = 32 >> s;
      const bool up = (lane & half) != 0;
      float pzr = __shfl_xor(zr, half);
      float pzi = __shfl_xor(zi, half);
      float pyr = __shfl_xor(yr, half);
      float pyi = __shfl_xor(yi, half);
      float tzr = up ? pzr - zr : zr + pzr;
      float tzi = up ? pzi - zi : zi + pzi;
      float tyr = up ? pyr - yr : yr + pyr;
      float tyi = up ? pyi - yi : yi + pyi;
      const float c = twc[s], sn = tws[s];
      zr = tzr * c - tzi * sn;
      zi = tzr * sn + tzi * c;
      yr = tyr * c - tyi * sn;
      yi = tyr * sn + tyi * c;
    }
    float mzr = __shfl(zr, plane), mzi = __shfl(zi, plane);
    float myr = __shfl(yr, plane), myi = __shfl(yi, plane);
    if (f <= 32) {
      float ar = 0.5f * (zr + mzr), ai = 0.5f * (zi - mzi);
      float br = 0.5f * (zi + mzi), bi = 0.5f * (mzr - zr);
      float cr = 0.5f * (yr + myr), ci = 0.5f * (yi - myi);
      float dr = 0.5f * (yi + myi), di = 0.5f * (myr - yr);
      re1[f * 65 + h0] = ar;     im1[f * 65 + h0] = ai;
      re1[f * 65 + h0 + 1] = br; im1[f * 65 + h0 + 1] = bi;
      re1[f * 65 + h0 + 2] = cr; im1[f * 65 + h0 + 2] = ci;
      re1[f * 65 + h0 + 3] = dr; im1[f * 65 + h0 + 3] = di;
    }
  }
  __syncthreads();

  float msum = 0.f;
#pragma unroll 1
  for (int i = 0; i < 4; ++i) {
    const int kv1 = wv + 8 * i;
    const int kv2 = kv1 + 4;
    const float w1 = (kv1 == 0) ? 1.f : 2.f;
    float ar = re1[kv1 * 65 + lane];
    float ai = im1[kv1 * 65 + lane];
    float br = re1[kv2 * 65 + lane];
    float bi = im1[kv2 * 65 + lane];
#pragma unroll
    for (int s = 0; s < 6; ++s) {
      const int half = 32 >> s;
      const bool up = (lane & half) != 0;
      float par = __shfl_xor(ar, half);
      float pai = __shfl_xor(ai, half);
      float pbr = __shfl_xor(br, half);
      float pbi = __shfl_xor(bi, half);
      float tar = up ? par - ar : ar + par;
      float tai = up ? pai - ai : ai + pai;
      float tbr = up ? pbr - br : br + pbr;
      float tbi = up ? pbi - bi : bi + pbi;
      const float c = twc[s], sn = tws[s];
      ar = tar * c - tai * sn;
      ai = tar * sn + tai * c;
      br = tbr * c - tbi * sn;
      bi = tbr * sn + tbi * c;
    }
    msum += w1 * sqrtf(ar * ar + ai * ai) + 2.f * sqrtf(br * br + bi * bi);
  }
  if (wv == 0) {
    float ar = re1[32 * 65 + lane];
    float ai = im1[32 * 65 + lane];
    FFT6(ar, ai);
    msum += sqrtf(ar * ar + ai * ai);
  }

  msum = wave_sum(msum);
  lsum = wave_sum(lsum);
  if (lane == 0) { redA[wv] = msum; redB[wv] = lsum; }
  __syncthreads();
  if (tid == 0) {
    float e = redA[0] + redA[1] + redA[2] + redA[3];
    float m = redB[0] + redB[1] + redB[2] + redB[3];
    energy[bc] = e * (1.f / 4096.f);
    meanx[bc] = m * (1.f / 4096.f);
  }
}

// ---------------------------------------------------------------------------
// Kernel C: fused ReceptiveFieldAttentionConv.
// R9 = R8 structure (512 blocks, icg-split-2, P=2, bf16 pair-packed oc
// weights) with ALL fp32 divisions replaced by v_rcp_f32 (silu/sigm were
// compiling to ~10-instr IEEE div sequences; 18 divs per thread*icg was
// ~25% of the VALU work).
// ---------------------------------------------------------------------------
__global__ __launch_bounds__(256) void k_rfa(
    const float* __restrict__ x,
    const float* __restrict__ sc_w, const float* __restrict__ sc_b,
    const float* __restrict__ ac_w, const float* __restrict__ ac_b,
    const float* __restrict__ oc_w, const float* __restrict__ oc_b,
    const float* __restrict__ bn_g, const float* __restrict__ bn_b,
    const float* __restrict__ bn_m, const float* __restrict__ bn_v,
    float* __restrict__ xrfa) {
  __shared__ __align__(16) float scwp[16 * 9 * 12];     // taps 0..8, bias at [9]
  __shared__ __align__(16) float mp[16 * 24];           // acw [0..8], acb [12..20]
  __shared__ __align__(16) unsigned ocwb[16 * 8 * 12];  // bf16 pair-packed
  __shared__ float red[128 * 33];                       // icg-half merge
  const int blk = blockIdx.x;          // 512 blocks: 16 bands x 4 g x 8 b
  const int band = blk & 15;
  const int g = (blk >> 4) & 3;
  const int b = blk >> 6;
  const int tid = threadIdx.x;
  const int lane = tid & 63;
  const int wv = tid >> 6;             // 0..3
  const int wp = wv & 1;               // row-pair within band
  const int half = wv >> 1;            // icg half

  for (int i = tid; i < 1296; i += 256) {
    int icg = i / 81, rem = i - icg * 81;
    int j = rem / 9, t = rem - j * 9;
    scwp[icg * 108 + j * 12 + t] = sc_w[(g * 144 + icg * 9 + j) * 9 + t];
  }
  if (tid < 144) {
    int icg = tid / 9, j = tid - icg * 9;
    scwp[icg * 108 + j * 12 + 9] = sc_b[g * 144 + tid];
    mp[icg * 24 + j] = ac_w[g * 144 + tid];
    mp[icg * 24 + 12 + j] = ac_b[g * 144 + tid];
  }
  for (int i = tid; i < 1152; i += 256) {
    int icg = i / 72, rem = i - icg * 72;
    int o2 = rem / 9, j = rem - o2 * 9;
    float w0 = oc_w[((g * 16 + 2 * o2) * 16 + icg) * 9 + j];
    float w1 = oc_w[((g * 16 + 2 * o2 + 1) * 16 + icg) * 9 + j];
    ocwb[icg * 96 + o2 * 12 + j] = bf16r(w0) | (bf16r(w1) << 16);
  }
  __syncthreads();

  const int r0 = band * 4 + wp * 2;
  const int w = lane;
  const bool vW = w > 0, vE = w < 63;
  float acc0[16], acc1[16];
#pragma unroll
  for (int i = 0; i < 16; ++i) { acc0[i] = 0.f; acc1[i] = 0.f; }

  const float* xg = x + ((size_t)(b * 64 + g * 16)) * 4096 + w;
  const int icg0 = half * 8;

#pragma unroll 1
  for (int ii = 0; ii < 8; ++ii) {
    const int icg = icg0 + ii;
    const float* xc = xg + icg * 4096;
    float n[12];
#pragma unroll
    for (int t = 0; t < 4; ++t) {
      int h = r0 - 1 + t;
      bool vh = (h >= 0) && (h < 64);
      const float* row = xc + h * 64;
      n[t * 3 + 0] = (vh && vW) ? row[-1] : 0.f;
      n[t * 3 + 1] = vh ? row[0] : 0.f;
      n[t * 3 + 2] = (vh && vE) ? row[1] : 0.f;
    }
    float rs0 = n[0] + n[1] + n[2];
    float rs1 = n[3] + n[4] + n[5];
    float rs2 = n[6] + n[7] + n[8];
    float rs3 = n[9] + n[10] + n[11];
    float ap0 = (rs0 + rs1 + rs2) * (1.f / 9.f);
    float ap1 = (rs1 + rs2 + rs3) * (1.f / 9.f);

    float aw[12], ab[12];
    *(float4*)&aw[0] = *(const float4*)&mp[icg * 24];
    *(float4*)&aw[4] = *(const float4*)&mp[icg * 24 + 4];
    *(float4*)&aw[8] = *(const float4*)&mp[icg * 24 + 8];
    *(float4*)&ab[0] = *(const float4*)&mp[icg * 24 + 12];
    *(float4*)&ab[4] = *(const float4*)&mp[icg * 24 + 16];
    *(float4*)&ab[8] = *(const float4*)&mp[icg * 24 + 20];

    float f0[9], f1[9], a0[9], a1[9];
    float amax0 = -1e30f, amax1 = -1e30f;
#pragma unroll
    for (int j = 0; j < 9; ++j) {
      float wt[12];
      *(float4*)&wt[0] = *(const float4*)&scwp[icg * 108 + j * 12];
      *(float4*)&wt[4] = *(const float4*)&scwp[icg * 108 + j * 12 + 4];
      *(float4*)&wt[8] = *(const float4*)&scwp[icg * 108 + j * 12 + 8];
      float p0 = wt[9], p1 = wt[9];
#pragma unroll
      for (int t = 0; t < 9; ++t) {
        p0 = fmaf(n[t], wt[t], p0);       // rows 0..2
        p1 = fmaf(n[t + 3], wt[t], p1);   // rows 1..3
      }
      f0[j] = silu_f(p0);
      f1[j] = silu_f(p1);
      float v0 = fmaf(ap0, aw[j], ab[j]);
      float v1 = fmaf(ap1, aw[j], ab[j]);
      a0[j] = v0; a1[j] = v1;
      amax0 = fmaxf(amax0, v0);
      amax1 = fmaxf(amax1, v1);
    }
    float es0 = 0.f, es1 = 0.f;
    float p0[9], p1[9];
#pragma unroll
    for (int j = 0; j < 9; ++j) {
      float e0 = __expf(a0[j] - amax0);
      float e1 = __expf(a1[j] - amax1);
      es0 += e0; es1 += e1;
      p0[j] = f0[j] * e0;
      p1[j] = f1[j] * e1;
    }
    float i0 = frcp(es0);
    float i1 = frcp(es1);
#pragma unroll
    for (int j = 0; j < 9; ++j) { p0[j] *= i0; p1[j] *= i1; }

#pragma unroll
    for (int o2 = 0; o2 < 8; ++o2) {
      unsigned u[12];
      *(uint4*)&u[0] = *(const uint4*)&ocwb[icg * 96 + o2 * 12];
      *(uint4*)&u[4] = *(const uint4*)&ocwb[icg * 96 + o2 * 12 + 4];
      *(uint4*)&u[8] = *(const uint4*)&ocwb[icg * 96 + o2 * 12 + 8];
      float se0 = 0.f, so0 = 0.f, se1 = 0.f, so1 = 0.f;
#pragma unroll
      for (int j = 0; j < 9; ++j) {
        float we = __uint_as_float(u[j] << 16);          // oco even
        float wo = __uint_as_float(u[j] & 0xFFFF0000u);  // oco odd
        se0 = fmaf(p0[j], we, se0);
        so0 = fmaf(p0[j], wo, so0);
        se1 = fmaf(p1[j], we, se1);
        so1 = fmaf(p1[j], wo, so1);
      }
      acc0[2 * o2] += se0;
      acc0[2 * o2 + 1] += so0;
      acc1[2 * o2] += se1;
      acc1[2 * o2 + 1] += so1;
    }
  }

  const int rid = wp * 64 + lane;
  if (half == 1) {
#pragma unroll
    for (int k = 0; k < 16; ++k) {
      red[rid * 33 + k] = acc0[k];
      red[rid * 33 + 16 + k] = acc1[k];
    }
  }
  __syncthreads();
  if (half == 0) {
#pragma unroll
    for (int k = 0; k < 16; ++k) {
      acc0[k] += red[rid * 33 + k];
      acc1[k] += red[rid * 33 + 16 + k];
    }
    float* op = xrfa + ((size_t)(b * 64 + g * 16)) * 4096 + r0 * 64 + w;
#pragma unroll
    for (int oco = 0; oco < 16; ++oco) {
      int oc = g * 16 + oco;
      float s = bn_g[oc] * rsqrtf(bn_v[oc] + EPS);
      float bb = bn_b[oc] - bn_m[oc] * s;
      float ob = oc_b[oc];
      float v0 = fmaf(acc0[oco] + ob, s, bb);
      float v1 = fmaf(acc1[oco] + ob, s, bb);
      op[oco * 4096] = silu_f(v0);
      op[oco * 4096 + 64] = silu_f(v1);
    }
  }
}

// ---------------------------------------------------------------------------
// Kernel D: final 1x1 conv + BN + SiLU, with the channel-attention head
// FUSED (each block recomputes the tiny attn for its batch from
// energy/meanx during weight staging -> no separate k_attn launch, no s2
// global round-trip).
// ---------------------------------------------------------------------------
__global__ __launch_bounds__(256) void k_fuse(
    const float* __restrict__ x, const float* __restrict__ xrfa,
    const float* __restrict__ energy, const float* __restrict__ meanx,
    const float* __restrict__ ex_w, const float* __restrict__ ey_w,
    const float* __restrict__ ez_w, const float* __restrict__ ff_w,
    const float* __restrict__ ff_b, const float* __restrict__ g1_w,
    const float* __restrict__ g1_b, const float* __restrict__ g2_w,
    const float* __restrict__ g2_b,
    const float* __restrict__ fu_w, const float* __restrict__ fu_b,
    const float* __restrict__ bn_g, const float* __restrict__ bn_b,
    const float* __restrict__ bn_m, const float* __restrict__ bn_v,
    float* __restrict__ out) {
  __shared__ __align__(16) float fw[4096];
  __shared__ float s2l[64];
  __shared__ float e[64], mx[64], my[64], mz[64];
  __shared__ float ax[64], ay[64], az[64], af[64], h1[16];
  const int blk = blockIdx.x;          // 512 blocks
  const int tid = threadIdx.x;
  const int sloc = tid & 63;
  const int ocq = tid >> 6;            // oc octet 0..3
  const int b = blk >> 6;
  const int sp = (blk & 63) * 64 + sloc;
  const int c = tid;                   // attn channel (c < 64 active)

  for (int i = tid; i < 1024; i += 256)
    ((float4*)fw)[i] = ((const float4*)fu_w)[i];
  if (c < 64) {
    e[c] = energy[b * 64 + c];
    mx[c] = meanx[b * 64 + c];
  }
  __syncthreads();
  // ---- attention head (replicated per block; ~2k FLOP) ----
  if (c < 64) {
    int rank = 0;
    float ec = e[c];
    for (int i = 0; i < 64; ++i) {
      float ei = e[i];
      rank += (ei > ec) || (ei == ec && i < c);
    }
    float mask = (rank < 32) ? 1.f : 0.f;
    my[c] = mx[c] * mask;
    mz[c] = mx[c] * (1.f - mask);
  }
  __syncthreads();
  if (c < 64) {
    float l, r, m;
    l = (c > 0) ? mx[c - 1] : 0.f; m = mx[c]; r = (c < 63) ? mx[c + 1] : 0.f;
    ax[c] = sigm_f(ex_w[0] * l + ex_w[1] * m + ex_w[2] * r);
    l = (c > 0) ? my[c - 1] : 0.f; m = my[c]; r = (c < 63) ? my[c + 1] : 0.f;
    ay[c] = sigm_f(ey_w[0] * l + ey_w[1] * m + ey_w[2] * r);
    l = (c > 0) ? mz[c - 1] : 0.f; m = mz[c]; r = (c < 63) ? mz[c + 1] : 0.f;
    az[c] = sigm_f(ez_w[0] * l + ez_w[1] * m + ez_w[2] * r);
  }
  __syncthreads();
  if (c < 64) {
    int gg = c >> 4;
    float acc = ff_b[c];
#pragma unroll
    for (int i = 0; i < 32; ++i) {
      int ch = gg * 32 + i;
      float v = (ch < 64) ? ay[ch] : az[ch - 64];
      acc = fmaf(v, ff_w[c * 32 + i], acc);
    }
    af[c] = acc;
  }
  __syncthreads();
  if (c < 16) {
    float a = g1_b[c];
#pragma unroll
    for (int i = 0; i < 64; ++i) a = fmaf(af[i], g1_w[c * 128 + i], a);
#pragma unroll
    for (int i = 0; i < 64; ++i) a = fmaf(ax[i], g1_w[c * 128 + 64 + i], a);
    h1[c] = silu_f(a);
  }
  __syncthreads();
  if (c < 64) {
    float gv = g2_b[c];
#pragma unroll
    for (int o = 0; o < 16; ++o) gv = fmaf(h1[o], g2_w[c * 16 + o], gv);
    gv = sigm_f(gv);
    s2l[c] = gv * af[c] + (1.f - gv) * ax[c];
  }

  // ---- main 1x1 conv ----
  const float* xr = xrfa + (size_t)b * 64 * 4096 + sp;
  const float* xp = x + (size_t)b * 64 * 4096 + sp;
  float va[64], vb[64];
#pragma unroll
  for (int i = 0; i < 64; ++i) va[i] = xr[i * 4096];
#pragma unroll
  for (int i = 0; i < 64; ++i) vb[i] = xp[i * 4096];
  __syncthreads();
#pragma unroll
  for (int i = 0; i < 64; ++i) vb[i] *= s2l[i];

  float* op = out + (size_t)b * 32 * 4096 + sp;
#pragma unroll 1
  for (int o = 0; o < 8; ++o) {
    const int oc = ocq * 8 + o;
    const float* wr = &fw[oc * 128];
    float a = 0.f;
#pragma unroll
    for (int q = 0; q < 16; ++q) {
      float4 w4 = *(const float4*)&wr[q * 4];
      a = fmaf(va[q * 4 + 0], w4.x, a);
      a = fmaf(va[q * 4 + 1], w4.y, a);
      a = fmaf(va[q * 4 + 2], w4.z, a);
      a = fmaf(va[q * 4 + 3], w4.w, a);
    }
#pragma unroll
    for (int q = 0; q < 16; ++q) {
      float4 w4 = *(const float4*)&wr[64 + q * 4];
      a = fmaf(vb[q * 4 + 0], w4.x, a);
      a = fmaf(vb[q * 4 + 1], w4.y, a);
      a = fmaf(vb[q * 4 + 2], w4.z, a);
      a = fmaf(vb[q * 4 + 3], w4.w, a);
    }
    float s = bn_g[oc] * rsqrtf(bn_v[oc] + EPS);
    float v = a + fu_b[oc];
    v = fmaf(v, s, bn_b[oc] - bn_m[oc] * s);
    op[oc * 4096] = silu_f(v);
  }
}

extern "C" void kernel_launch(void* const* d_in, const int* in_sizes, int n_in,
                              void* d_out, int out_size, void* d_ws, size_t ws_size,
                              hipStream_t stream) {
  const float* x       = (const float*)d_in[0];
  const float* sc_w    = (const float*)d_in[1];
  const float* sc_b    = (const float*)d_in[2];
  const float* ac_w    = (const float*)d_in[3];
  const float* ac_b    = (const float*)d_in[4];
  const float* oc_w    = (const float*)d_in[5];
  const float* oc_b    = (const float*)d_in[6];
  const float* oc_bn_g = (const float*)d_in[7];
  const float* oc_bn_b = (const float*)d_in[8];
  const float* oc_bn_m = (const float*)d_in[9];
  const float* oc_bn_v = (const float*)d_in[10];
  const float* ex_w    = (const float*)d_in[11];
  const float* ey_w    = (const float*)d_in[12];
  const float* ez_w    = (const float*)d_in[13];
  const float* ff_w    = (const float*)d_in[14];
  const float* ff_b    = (const float*)d_in[15];
  const float* g1_w    = (const float*)d_in[16];
  const float* g1_b    = (const float*)d_in[17];
  const float* g2_w    = (const float*)d_in[18];
  const float* g2_b    = (const float*)d_in[19];
  const float* fu_w    = (const float*)d_in[20];
  const float* fu_b    = (const float*)d_in[21];
  const float* fu_bn_g = (const float*)d_in[22];
  const float* fu_bn_b = (const float*)d_in[23];
  const float* fu_bn_m = (const float*)d_in[24];
  const float* fu_bn_v = (const float*)d_in[25];

  float* ws     = (float*)d_ws;
  float* energy = ws;            // 512 floats
  float* meanx  = ws + 512;      // 512 floats
  float* xrfa   = ws + 2048;     // 8*64*4096 floats

  k_dft<<<512, 256, 0, stream>>>(x, energy, meanx);
  k_rfa<<<512, 256, 0, stream>>>(x, sc_w, sc_b, ac_w, ac_b, oc_w, oc_b,
                                 oc_bn_g, oc_bn_b, oc_bn_m, oc_bn_v, xrfa);
  k_fuse<<<512, 256, 0, stream>>>(x, xrfa, energy, meanx,
                                  ex_w, ey_w, ez_w, ff_w, ff_b,
                                  g1_w, g1_b, g2_w, g2_b,
                                  fu_w, fu_b,
                                  fu_bn_g, fu_bn_b, fu_bn_m, fu_bn_v,
                                  (float*)d_out);
}

// Round 11
// 156.712 us; speedup vs baseline: 1.2806x; 1.0769x over previous
//
#include <hip/hip_runtime.h>
#include <math.h>

#define EPS 1e-5f

__device__ __forceinline__ float wave_sum(float v) {
  v += __shfl_down(v, 32);
  v += __shfl_down(v, 16);
  v += __shfl_down(v, 8);
  v += __shfl_down(v, 4);
  v += __shfl_down(v, 2);
  v += __shfl_down(v, 1);
  return v;
}

// fast reciprocal (v_rcp_f32, ~1 ulp)
__device__ __forceinline__ float frcp(float x) { return __builtin_amdgcn_rcpf(x); }
__device__ __forceinline__ float silu_f(float v) { return v * frcp(1.f + __expf(-v)); }
__device__ __forceinline__ float sigm_f(float v) { return frcp(1.f + __expf(-v)); }

__device__ __forceinline__ unsigned bf16r(float v) {   // RNE fp32 -> bf16 bits
  unsigned u = __float_as_uint(v);
  return (u + 0x7FFFu + ((u >> 16) & 1u)) >> 16;
}

__device__ __forceinline__ int bitrev6(int v) {
  return ((v & 1) << 5) | ((v & 2) << 3) | ((v & 4) << 1) |
         ((v & 8) >> 1) | ((v & 16) >> 3) | ((v & 32) >> 5);
}

#define FFT6(zr, zi)                                           \
  do {                                                         \
    _Pragma("unroll") for (int s = 0; s < 6; ++s) {            \
      const int half = 32 >> s;                                \
      const bool up = (lane & half) != 0;                      \
      float pr = __shfl_xor(zr, half);                         \
      float pi = __shfl_xor(zi, half);                         \
      float tr = up ? pr - zr : zr + pr;                       \
      float ti = up ? pi - zi : zi + pi;                       \
      const float c = twc[s], sn = tws[s];                     \
      zr = tr * c - ti * sn;                                   \
      zi = tr * sn + ti * c;                                   \
    }                                                          \
  } while (0)

// LDS overlay: the rfa path and dft path never coexist in one block.
struct SRfa {
  float scwp[16 * 9 * 12];     // sc taps 0..8, bias at [9]
  float mp[16 * 24];           // acw [0..8], acb [12..20]
  unsigned ocwb[16 * 8 * 12];  // bf16 pair-packed oc weights
  float red[128 * 33];         // icg-half merge
};
struct SDft {
  float re1[33 * 65];
  float im1[33 * 65];
  float redA[4], redB[4];
};
union SMem { SRfa r; SDft d; };

// ---------------------------------------------------------------------------
// k_main: blocks 0..511 run the RFA path, 512..1023 the DFT path.
// The two are independent (k_fuse consumes both); merging them lets the
// ~18us DFT hide under the ~38us RFA instead of serializing.
// ---------------------------------------------------------------------------
__global__ __launch_bounds__(256) void k_main(
    const float* __restrict__ x,
    const float* __restrict__ sc_w, const float* __restrict__ sc_b,
    const float* __restrict__ ac_w, const float* __restrict__ ac_b,
    const float* __restrict__ oc_w, const float* __restrict__ oc_b,
    const float* __restrict__ bn_g, const float* __restrict__ bn_b,
    const float* __restrict__ bn_m, const float* __restrict__ bn_v,
    float* __restrict__ xrfa,
    float* __restrict__ energy, float* __restrict__ meanx) {
  __shared__ SMem sm;
  const int tid = threadIdx.x;
  const int lane = tid & 63;
  const int wv = tid >> 6;             // 0..3

  if (blockIdx.x < 512) {
    // ================= RFA path =================
    const int blk = blockIdx.x;        // 16 bands x 4 g x 8 b
    const int band = blk & 15;
    const int g = (blk >> 4) & 3;
    const int b = blk >> 6;
    const int wp = wv & 1;             // row-pair within band
    const int half = wv >> 1;          // icg half
    float* scwp = sm.r.scwp;
    float* mp = sm.r.mp;
    unsigned* ocwb = sm.r.ocwb;
    float* red = sm.r.red;

    for (int i = tid; i < 1296; i += 256) {
      int icg = i / 81, rem = i - icg * 81;
      int j = rem / 9, t = rem - j * 9;
      scwp[icg * 108 + j * 12 + t] = sc_w[(g * 144 + icg * 9 + j) * 9 + t];
    }
    if (tid < 144) {
      int icg = tid / 9, j = tid - icg * 9;
      scwp[icg * 108 + j * 12 + 9] = sc_b[g * 144 + tid];
      mp[icg * 24 + j] = ac_w[g * 144 + tid];
      mp[icg * 24 + 12 + j] = ac_b[g * 144 + tid];
    }
    for (int i = tid; i < 1152; i += 256) {
      int icg = i / 72, rem = i - icg * 72;
      int o2 = rem / 9, j = rem - o2 * 9;
      float w0 = oc_w[((g * 16 + 2 * o2) * 16 + icg) * 9 + j];
      float w1 = oc_w[((g * 16 + 2 * o2 + 1) * 16 + icg) * 9 + j];
      ocwb[icg * 96 + o2 * 12 + j] = bf16r(w0) | (bf16r(w1) << 16);
    }
    __syncthreads();

    const int r0 = band * 4 + wp * 2;
    const int w = lane;
    const bool vW = w > 0, vE = w < 63;
    float acc0[16], acc1[16];
#pragma unroll
    for (int i = 0; i < 16; ++i) { acc0[i] = 0.f; acc1[i] = 0.f; }

    const float* xg = x + ((size_t)(b * 64 + g * 16)) * 4096 + w;
    const int icg0 = half * 8;

#pragma unroll 1
    for (int ii = 0; ii < 8; ++ii) {
      const int icg = icg0 + ii;
      const float* xc = xg + icg * 4096;
      float n[12];
#pragma unroll
      for (int t = 0; t < 4; ++t) {
        int h = r0 - 1 + t;
        bool vh = (h >= 0) && (h < 64);
        const float* row = xc + h * 64;
        n[t * 3 + 0] = (vh && vW) ? row[-1] : 0.f;
        n[t * 3 + 1] = vh ? row[0] : 0.f;
        n[t * 3 + 2] = (vh && vE) ? row[1] : 0.f;
      }
      float rs0 = n[0] + n[1] + n[2];
      float rs1 = n[3] + n[4] + n[5];
      float rs2 = n[6] + n[7] + n[8];
      float rs3 = n[9] + n[10] + n[11];
      float ap0 = (rs0 + rs1 + rs2) * (1.f / 9.f);
      float ap1 = (rs1 + rs2 + rs3) * (1.f / 9.f);

      float aw[12], ab[12];
      *(float4*)&aw[0] = *(const float4*)&mp[icg * 24];
      *(float4*)&aw[4] = *(const float4*)&mp[icg * 24 + 4];
      *(float4*)&aw[8] = *(const float4*)&mp[icg * 24 + 8];
      *(float4*)&ab[0] = *(const float4*)&mp[icg * 24 + 12];
      *(float4*)&ab[4] = *(const float4*)&mp[icg * 24 + 16];
      *(float4*)&ab[8] = *(const float4*)&mp[icg * 24 + 20];

      // fused sc-conv + softmax-numerator pass (no max-shift: av bounded,
      // softmax is shift-invariant so this is mathematically identical)
      float p0[9], p1[9];
      float es0 = 0.f, es1 = 0.f;
#pragma unroll
      for (int j = 0; j < 9; ++j) {
        float wt[12];
        *(float4*)&wt[0] = *(const float4*)&scwp[icg * 108 + j * 12];
        *(float4*)&wt[4] = *(const float4*)&scwp[icg * 108 + j * 12 + 4];
        *(float4*)&wt[8] = *(const float4*)&scwp[icg * 108 + j * 12 + 8];
        float q0 = wt[9], q1 = wt[9];
#pragma unroll
        for (int t = 0; t < 9; ++t) {
          q0 = fmaf(n[t], wt[t], q0);       // rows 0..2
          q1 = fmaf(n[t + 3], wt[t], q1);   // rows 1..3
        }
        float e0 = __expf(fmaf(ap0, aw[j], ab[j]));
        float e1 = __expf(fmaf(ap1, aw[j], ab[j]));
        es0 += e0; es1 += e1;
        p0[j] = silu_f(q0) * e0;
        p1[j] = silu_f(q1) * e1;
      }
      float i0 = frcp(es0);
      float i1 = frcp(es1);
#pragma unroll
      for (int j = 0; j < 9; ++j) { p0[j] *= i0; p1[j] *= i1; }

#pragma unroll
      for (int o2 = 0; o2 < 8; ++o2) {
        unsigned u[12];
        *(uint4*)&u[0] = *(const uint4*)&ocwb[icg * 96 + o2 * 12];
        *(uint4*)&u[4] = *(const uint4*)&ocwb[icg * 96 + o2 * 12 + 4];
        *(uint4*)&u[8] = *(const uint4*)&ocwb[icg * 96 + o2 * 12 + 8];
        float se0 = 0.f, so0 = 0.f, se1 = 0.f, so1 = 0.f;
#pragma unroll
        for (int j = 0; j < 9; ++j) {
          float we = __uint_as_float(u[j] << 16);          // oco even
          float wo = __uint_as_float(u[j] & 0xFFFF0000u);  // oco odd
          se0 = fmaf(p0[j], we, se0);
          so0 = fmaf(p0[j], wo, so0);
          se1 = fmaf(p1[j], we, se1);
          so1 = fmaf(p1[j], wo, so1);
        }
        acc0[2 * o2] += se0;
        acc0[2 * o2 + 1] += so0;
        acc1[2 * o2] += se1;
        acc1[2 * o2 + 1] += so1;
      }
    }

    const int rid = wp * 64 + lane;
    if (half == 1) {
#pragma unroll
      for (int k = 0; k < 16; ++k) {
        red[rid * 33 + k] = acc0[k];
        red[rid * 33 + 16 + k] = acc1[k];
      }
    }
    __syncthreads();
    if (half == 0) {
#pragma unroll
      for (int k = 0; k < 16; ++k) {
        acc0[k] += red[rid * 33 + k];
        acc1[k] += red[rid * 33 + 16 + k];
      }
      float* op = xrfa + ((size_t)(b * 64 + g * 16)) * 4096 + r0 * 64 + w;
#pragma unroll
      for (int oco = 0; oco < 16; ++oco) {
        int oc = g * 16 + oco;
        float s = bn_g[oc] * rsqrtf(bn_v[oc] + EPS);
        float bb = bn_b[oc] - bn_m[oc] * s;
        float ob = oc_b[oc];
        float v0 = fmaf(acc0[oco] + ob, s, bb);
        float v1 = fmaf(acc1[oco] + ob, s, bb);
        op[oco * 4096] = silu_f(v0);
        op[oco * 4096 + 64] = silu_f(v1);
      }
    }
  } else {
    // ================= DFT path =================
    const int bc = blockIdx.x - 512;   // b*64 + c
    float* re1 = sm.d.re1;
    float* im1 = sm.d.im1;
    const float* xp = x + (size_t)bc * 4096;

    float twc[6], tws[6];
#pragma unroll
    for (int s = 0; s < 6; ++s) {
      int half = 32 >> s;
      if (lane & half) {
        float ang = -6.283185307179586f * (float)((lane & (half - 1)) << s) / 64.f;
        float sv, cv;
        __sincosf(ang, &sv, &cv);
        twc[s] = cv;
        tws[s] = sv;
      } else {
        twc[s] = 1.f;
        tws[s] = 0.f;
      }
    }

    const int f = bitrev6(lane);
    const int fm = (64 - f) & 63;
    const int plane = bitrev6(fm);

    float lsum = 0.f;
#pragma unroll 1
    for (int rp = 0; rp < 4; ++rp) {
      const int h0 = wv * 16 + rp * 4;
      float x0 = xp[h0 * 64 + lane];
      float x1 = xp[(h0 + 1) * 64 + lane];
      float x2 = xp[(h0 + 2) * 64 + lane];
      float x3 = xp[(h0 + 3) * 64 + lane];
      lsum += x0 + x1 + x2 + x3;
      float zr = x0, zi = x1, yr = x2, yi = x3;
#pragma unroll
      for (int s = 0; s < 6; ++s) {
        const int half = 32 >> s;
        const bool up = (lane & half) != 0;
        float pzr = __shfl_xor(zr, half);
        float pzi = __shfl_xor(zi, half);
        float pyr = __shfl_xor(yr, half);
        float pyi = __shfl_xor(yi, half);
        float tzr = up ? pzr - zr : zr + pzr;
        float tzi = up ? pzi - zi : zi + pzi;
        float tyr = up ? pyr - yr : yr + pyr;
        float tyi = up ? pyi - yi : yi + pyi;
        const float c = twc[s], sn = tws[s];
        zr = tzr * c - tzi * sn;
        zi = tzr * sn + tzi * c;
        yr = tyr * c - tyi * sn;
        yi = tyr * sn + tyi * c;
      }
      float mzr = __shfl(zr, plane), mzi = __shfl(zi, plane);
      float myr = __shfl(yr, plane), myi = __shfl(yi, plane);
      if (f <= 32) {
        float ar = 0.5f * (zr + mzr), ai = 0.5f * (zi - mzi);
        float br = 0.5f * (zi + mzi), bi = 0.5f * (mzr - zr);
        float cr = 0.5f * (yr + myr), ci = 0.5f * (yi - myi);
        float dr = 0.5f * (yi + myi), di = 0.5f * (myr - yr);
        re1[f * 65 + h0] = ar;     im1[f * 65 + h0] = ai;
        re1[f * 65 + h0 + 1] = br; im1[f * 65 + h0 + 1] = bi;
        re1[f * 65 + h0 + 2] = cr; im1[f * 65 + h0 + 2] = ci;
        re1[f * 65 + h0 + 3] = dr; im1[f * 65 + h0 + 3] = di;
      }
    }
    __syncthreads();

    float msum = 0.f;
#pragma unroll 1
    for (int i = 0; i < 4; ++i) {
      const int kv1 = wv + 8 * i;
      const int kv2 = kv1 + 4;
      const float w1 = (kv1 == 0) ? 1.f : 2.f;
      float ar = re1[kv1 * 65 + lane];
      float ai = im1[kv1 * 65 + lane];
      float br = re1[kv2 * 65 + lane];
      float bi = im1[kv2 * 65 + lane];
#pragma unroll
      for (int s = 0; s < 6; ++s) {
        const int half = 32 >> s;
        const bool up = (lane & half) != 0;
        float par = __shfl_xor(ar, half);
        float pai = __shfl_xor(ai, half);
        float pbr = __shfl_xor(br, half);
        float pbi = __shfl_xor(bi, half);
        float tar = up ? par - ar : ar + par;
        float tai = up ? pai - ai : ai + pai;
        float tbr = up ? pbr - br : br + pbr;
        float tbi = up ? pbi - bi : bi + pbi;
        const float c = twc[s], sn = tws[s];
        ar = tar * c - tai * sn;
        ai = tar * sn + tai * c;
        br = tbr * c - tbi * sn;
        bi = tbr * sn + tbi * c;
      }
      msum += w1 * sqrtf(ar * ar + ai * ai) + 2.f * sqrtf(br * br + bi * bi);
    }
    if (wv == 0) {
      float ar = re1[32 * 65 + lane];
      float ai = im1[32 * 65 + lane];
      FFT6(ar, ai);
      msum += sqrtf(ar * ar + ai * ai);
    }

    msum = wave_sum(msum);
    lsum = wave_sum(lsum);
    if (lane == 0) { sm.d.redA[wv] = msum; sm.d.redB[wv] = lsum; }
    __syncthreads();
    if (tid == 0) {
      float e = sm.d.redA[0] + sm.d.redA[1] + sm.d.redA[2] + sm.d.redA[3];
      float m = sm.d.redB[0] + sm.d.redB[1] + sm.d.redB[2] + sm.d.redB[3];
      energy[bc] = e * (1.f / 4096.f);
      meanx[bc] = m * (1.f / 4096.f);
    }
  }
}

// ---------------------------------------------------------------------------
// Kernel D: final 1x1 conv + BN + SiLU with fused attention head (R9).
// ---------------------------------------------------------------------------
__global__ __launch_bounds__(256) void k_fuse(
    const float* __restrict__ x, const float* __restrict__ xrfa,
    const float* __restrict__ energy, const float* __restrict__ meanx,
    const float* __restrict__ ex_w, const float* __restrict__ ey_w,
    const float* __restrict__ ez_w, const float* __restrict__ ff_w,
    const float* __restrict__ ff_b, const float* __restrict__ g1_w,
    const float* __restrict__ g1_b, const float* __restrict__ g2_w,
    const float* __restrict__ g2_b,
    const float* __restrict__ fu_w, const float* __restrict__ fu_b,
    const float* __restrict__ bn_g, const float* __restrict__ bn_b,
    const float* __restrict__ bn_m, const float* __restrict__ bn_v,
    float* __restrict__ out) {
  __shared__ __align__(16) float fw[4096];
  __shared__ float s2l[64];
  __shared__ float e[64], mx[64], my[64], mz[64];
  __shared__ float ax[64], ay[64], az[64], af[64], h1[16];
  const int blk = blockIdx.x;          // 512 blocks
  const int tid = threadIdx.x;
  const int sloc = tid & 63;
  const int ocq = tid >> 6;            // oc octet 0..3
  const int b = blk >> 6;
  const int sp = (blk & 63) * 64 + sloc;
  const int c = tid;                   // attn channel (c < 64 active)

  for (int i = tid; i < 1024; i += 256)
    ((float4*)fw)[i] = ((const float4*)fu_w)[i];
  if (c < 64) {
    e[c] = energy[b * 64 + c];
    mx[c] = meanx[b * 64 + c];
  }
  __syncthreads();
  if (c < 64) {
    int rank = 0;
    float ec = e[c];
    for (int i = 0; i < 64; ++i) {
      float ei = e[i];
      rank += (ei > ec) || (ei == ec && i < c);
    }
    float mask = (rank < 32) ? 1.f : 0.f;
    my[c] = mx[c] * mask;
    mz[c] = mx[c] * (1.f - mask);
  }
  __syncthreads();
  if (c < 64) {
    float l, r, m;
    l = (c > 0) ? mx[c - 1] : 0.f; m = mx[c]; r = (c < 63) ? mx[c + 1] : 0.f;
    ax[c] = sigm_f(ex_w[0] * l + ex_w[1] * m + ex_w[2] * r);
    l = (c > 0) ? my[c - 1] : 0.f; m = my[c]; r = (c < 63) ? my[c + 1] : 0.f;
    ay[c] = sigm_f(ey_w[0] * l + ey_w[1] * m + ey_w[2] * r);
    l = (c > 0) ? mz[c - 1] : 0.f; m = mz[c]; r = (c < 63) ? mz[c + 1] : 0.f;
    az[c] = sigm_f(ez_w[0] * l + ez_w[1] * m + ez_w[2] * r);
  }
  __syncthreads();
  if (c < 64) {
    int gg = c >> 4;
    float acc = ff_b[c];
#pragma unroll
    for (int i = 0; i < 32; ++i) {
      int ch = gg * 32 + i;
      float v = (ch < 64) ? ay[ch] : az[ch - 64];
      acc = fmaf(v, ff_w[c * 32 + i], acc);
    }
    af[c] = acc;
  }
  __syncthreads();
  if (c < 16) {
    float a = g1_b[c];
#pragma unroll
    for (int i = 0; i < 64; ++i) a = fmaf(af[i], g1_w[c * 128 + i], a);
#pragma unroll
    for (int i = 0; i < 64; ++i) a = fmaf(ax[i], g1_w[c * 128 + 64 + i], a);
    h1[c] = silu_f(a);
  }
  __syncthreads();
  if (c < 64) {
    float gv = g2_b[c];
#pragma unroll
    for (int o = 0; o < 16; ++o) gv = fmaf(h1[o], g2_w[c * 16 + o], gv);
    gv = sigm_f(gv);
    s2l[c] = gv * af[c] + (1.f - gv) * ax[c];
  }

  const float* xr = xrfa + (size_t)b * 64 * 4096 + sp;
  const float* xp = x + (size_t)b * 64 * 4096 + sp;
  float va[64], vb[64];
#pragma unroll
  for (int i = 0; i < 64; ++i) va[i] = xr[i * 4096];
#pragma unroll
  for (int i = 0; i < 64; ++i) vb[i] = xp[i * 4096];
  __syncthreads();
#pragma unroll
  for (int i = 0; i < 64; ++i) vb[i] *= s2l[i];

  float* op = out + (size_t)b * 32 * 4096 + sp;
#pragma unroll 1
  for (int o = 0; o < 8; ++o) {
    const int oc = ocq * 8 + o;
    const float* wr = &fw[oc * 128];
    float a = 0.f;
#pragma unroll
    for (int q = 0; q < 16; ++q) {
      float4 w4 = *(const float4*)&wr[q * 4];
      a = fmaf(va[q * 4 + 0], w4.x, a);
      a = fmaf(va[q * 4 + 1], w4.y, a);
      a = fmaf(va[q * 4 + 2], w4.z, a);
      a = fmaf(va[q * 4 + 3], w4.w, a);
    }
#pragma unroll
    for (int q = 0; q < 16; ++q) {
      float4 w4 = *(const float4*)&wr[64 + q * 4];
      a = fmaf(vb[q * 4 + 0], w4.x, a);
      a = fmaf(vb[q * 4 + 1], w4.y, a);
      a = fmaf(vb[q * 4 + 2], w4.z, a);
      a = fmaf(vb[q * 4 + 3], w4.w, a);
    }
    float s = bn_g[oc] * rsqrtf(bn_v[oc] + EPS);
    float v = a + fu_b[oc];
    v = fmaf(v, s, bn_b[oc] - bn_m[oc] * s);
    op[oc * 4096] = silu_f(v);
  }
}

extern "C" void kernel_launch(void* const* d_in, const int* in_sizes, int n_in,
                              void* d_out, int out_size, void* d_ws, size_t ws_size,
                              hipStream_t stream) {
  const float* x       = (const float*)d_in[0];
  const float* sc_w    = (const float*)d_in[1];
  const float* sc_b    = (const float*)d_in[2];
  const float* ac_w    = (const float*)d_in[3];
  const float* ac_b    = (const float*)d_in[4];
  const float* oc_w    = (const float*)d_in[5];
  const float* oc_b    = (const float*)d_in[6];
  const float* oc_bn_g = (const float*)d_in[7];
  const float* oc_bn_b = (const float*)d_in[8];
  const float* oc_bn_m = (const float*)d_in[9];
  const float* oc_bn_v = (const float*)d_in[10];
  const float* ex_w    = (const float*)d_in[11];
  const float* ey_w    = (const float*)d_in[12];
  const float* ez_w    = (const float*)d_in[13];
  const float* ff_w    = (const float*)d_in[14];
  const float* ff_b    = (const float*)d_in[15];
  const float* g1_w    = (const float*)d_in[16];
  const float* g1_b    = (const float*)d_in[17];
  const float* g2_w    = (const float*)d_in[18];
  const float* g2_b    = (const float*)d_in[19];
  const float* fu_w    = (const float*)d_in[20];
  const float* fu_b    = (const float*)d_in[21];
  const float* fu_bn_g = (const float*)d_in[22];
  const float* fu_bn_b = (const float*)d_in[23];
  const float* fu_bn_m = (const float*)d_in[24];
  const float* fu_bn_v = (const float*)d_in[25];

  float* ws     = (float*)d_ws;
  float* energy = ws;            // 512 floats
  float* meanx  = ws + 512;      // 512 floats
  float* xrfa   = ws + 2048;     // 8*64*4096 floats

  k_main<<<1024, 256, 0, stream>>>(x, sc_w, sc_b, ac_w, ac_b, oc_w, oc_b,
                                   oc_bn_g, oc_bn_b, oc_bn_m, oc_bn_v,
                                   xrfa, energy, meanx);
  k_fuse<<<512, 256, 0, stream>>>(x, xrfa, energy, meanx,
                                  ex_w, ey_w, ez_w, ff_w, ff_b,
                                  g1_w, g1_b, g2_w, g2_b,
                                  fu_w, fu_b,
                                  fu_bn_g, fu_bn_b, fu_bn_m, fu_bn_v,
                                  (float*)d_out);
}